// Round 9
// baseline (139.324 us; speedup 1.0000x reference)
//
#include <hip/hip_runtime.h>
#include <math.h>

#define EMB_D 64
// ref fp32-rounding band (~1.6e-5) + screen err (bf16-split ~6e-6 + 64-ULP
// pack-trunc ~3.8e-6 => ~1e-5 per score); need >= 3.6e-5, keep 6e-5 (1.7x slack)
#define MARGIN 6.0e-5f
// score bias: biased = 0.5 + (wsq - 2*x.w) in (0.3, 0.7), strictly positive
// => IEEE positive floats compare as uints.  (validated r2..r7: passed)
#define SBIAS 0.5f

typedef float  f32x4  __attribute__((ext_vector_type(4)));
typedef short  bf16x8 __attribute__((ext_vector_type(8)));

__device__ __forceinline__ unsigned short f2bf(float f) {
    unsigned int u = __float_as_uint(f);
    return (unsigned short)((u + 0x7FFFu + ((u >> 16) & 1u)) >> 16);
}
__device__ __forceinline__ float bf2f(unsigned short h) {
    return __uint_as_float(((unsigned int)h) << 16);
}

union Pack8 { ushort u[8]; bf16x8 v; uint4 q; };

// 16-B-aligned bf16x8 load (LDS or global) via uint4
__device__ __forceinline__ bf16x8 ldbf8(const unsigned short* p) {
    union { uint4 u; bf16x8 v; } c;
    c.u = *(const uint4*)p;
    return c.v;
}

// async global->LDS DMA, 16B per lane.  LDS dst must be wave-uniform base +
// lane*16 (m104); our staging is exactly linear so this holds.
__device__ __forceinline__ void stage16(const void* g, void* l) {
    __builtin_amdgcn_global_load_lds(
        (const __attribute__((address_space(1))) unsigned int*)g,
        (__attribute__((address_space(3))) unsigned int*)l, 16, 0, 0);
}

// ---------------------------------------------------------------------------
// PREP-W: w -> bf16 hi/lo in MFMA-chunk-transposed order + wsq + zero loss.
// (unchanged, proven)
// ---------------------------------------------------------------------------
__global__ __launch_bounds__(256)
void vq_prepw_kernel(const float* __restrict__ w,
                     unsigned short* __restrict__ wt_hi,
                     unsigned short* __restrict__ wt_lo,
                     float* __restrict__ wsq, float* __restrict__ loss_out,
                     int K) {
    const int i = blockIdx.x * 256 + threadIdx.x;   // chunk id, K*8 total
    if (i == 0) loss_out[0] = 0.f;
    if (i >= K * 8) return;
    const int krow = i >> 3, q = i & 7;
    const int dest = ((krow >> 6) << 9) + (((krow >> 4) & 3) << 7) + (q << 4)
                   + (krow & 15);
    const float* src = w + (size_t)krow * EMB_D + q * 8;
    Pack8 h, l;
#pragma unroll
    for (int j = 0; j < 8; ++j) {
        const float f = src[j];
        h.u[j] = f2bf(f);
        l.u[j] = f2bf(f - bf2f(h.u[j]));
    }
    ((uint4*)wt_hi)[dest] = h.q;
    ((uint4*)wt_lo)[dest] = l.q;

    if (i < K) {   // wsq[i]: numpy-emulated fp32 sum(w_i^2)  [proven]
        const float* wr = w + (size_t)i * EMB_D;
        float r[8];
#pragma unroll
        for (int j = 0; j < 8; ++j) r[j] = __fmul_rn(wr[j], wr[j]);
#pragma unroll
        for (int t = 1; t < 8; ++t)
#pragma unroll
            for (int j = 0; j < 8; ++j)
                r[j] = __fadd_rn(r[j], __fmul_rn(wr[t * 8 + j], wr[t * 8 + j]));
        float a = __fadd_rn(__fadd_rn(r[0], r[1]), __fadd_rn(r[2], r[3]));
        float b = __fadd_rn(__fadd_rn(r[4], r[5]), __fadd_rn(r[6], r[7]));
        wsq[i] = __fadd_rn(a, b);
    }
}

// ---------------------------------------------------------------------------
// FUSED SCREEN + GATHER, v8 = v7 main loop restaged with global_load_lds:
//  - staging: __builtin_amdgcn_global_load_lds (16B) into a DOUBLE-buffered
//    32KB arena -> deletes all ds_write_b128 (-20% LDS pipe ops), deletes
//    the 16-VGPR register prefetch, and halves barriers: ONE __syncthreads
//    per segment (its vmcnt/lgkm drain covers both the seg's reads and the
//    next seg's in-flight DMA).  seg+1 DMA issues before compute -> a full
//    compute phase (~1000cy) hides the ~200cy L2 latency.
//  - layout satisfies m104: LDS dst = wave-uniform base + lane*16, linear.
//  - Mp1/Mp2 merge arrays overlay the dead staging arena (v4-proven trick);
//    LDS ~40KB -> still 4 blocks/CU.  launch_bounds (256,2): r7 proved the
//    (256,4) bound causes scratch spill (+18MB writes).
//  - selection/tail: unchanged from v7 (proven, absmax 3.8e-6).
// ---------------------------------------------------------------------------
__global__ __launch_bounds__(256, 2)
void vq_fused_kernel(const float* __restrict__ x,
                     const unsigned short* __restrict__ wt_hi,
                     const unsigned short* __restrict__ wt_lo,
                     const float* __restrict__ wsq,
                     const float* __restrict__ w,
                     float* __restrict__ out, float* __restrict__ loss_out,
                     int K, int N, float scale) {
    const int tid  = threadIdx.x;       // 0..255
    const int lane = tid & 63;
    const int wave = tid >> 6;          // 0..3
    const int quad = lane >> 4;
    const int c16  = lane & 15;
    const int rowbase = blockIdx.x * 64 + wave * 16;

    // staging arena: buf b at arena+b*16384 (hi 8KB, then lo 8KB)
    __shared__ __align__(16) char arena[32768];
    __shared__ float wsq_lds[1024];         // biased: wsq + SBIAS (4 KB)
    typedef unsigned MpArr[16][17];         // merge overlay (after seg loop)
    MpArr* Mp1 = (MpArr*)arena;             // 4x16x17x4 = 4352 B
    MpArr* Mp2 = (MpArr*)(arena + 4352);    // 4352 B
    __shared__ int kf[64], strow[64], k2row[64];

    const uint4* gh4 = (const uint4*)wt_hi;
    const uint4* gl4 = (const uint4*)wt_lo;

    {   // prologue: DMA seg 0 -> buf 0 (issue FIRST, overlap with A-frag work)
        uint4* bh = (uint4*)arena;
        uint4* bl = (uint4*)(arena + 8192);
        stage16(gh4 + tid,       bh + tid);
        stage16(gh4 + 256 + tid, bh + 256 + tid);
        stage16(gl4 + tid,       bl + tid);
        stage16(gl4 + 256 + tid, bl + 256 + tid);
    }

    // ---- A-frags: split x hi/lo in-register (this lane's 16 floats) ----
    const float* xrow = x + (size_t)(rowbase + c16) * EMB_D + quad * 8;
    Pack8 ah0, al0, ah1, al1;
#pragma unroll
    for (int j = 0; j < 8; ++j) {
        const float f0 = xrow[j];
        ah0.u[j] = f2bf(f0); al0.u[j] = f2bf(f0 - bf2f(ah0.u[j]));
        const float f1 = xrow[32 + j];
        ah1.u[j] = f2bf(f1); al1.u[j] = f2bf(f1 - bf2f(ah1.u[j]));
    }
    const bf16x8 AH0 = ah0.v, AL0 = al0.v, AH1 = ah1.v, AL1 = al1.v;

    {   // biased wsq into LDS (global wsq stays unbiased for exact paths)
        float4 a = ((const float4*)wsq)[tid];
        a.x += SBIAS; a.y += SBIAS; a.z += SBIAS; a.w += SBIAS;
        ((float4*)wsq_lds)[tid] = a;
    }

    // packed top-2 per acc-row
    unsigned s1v[4], s2v[4];
#pragma unroll
    for (int i = 0; i < 4; ++i) { s1v[i] = 0xFFFFFFFFu; s2v[i] = 0xFFFFFFFFu; }

    __syncthreads();                    // drains vmcnt -> buf0 ready

    const int nseg = K >> 6;            // 16
    for (int seg = 0; seg < nseg; ++seg) {
        const int cur = seg & 1;
        if (seg + 1 < nseg) {           // DMA next segment into other buffer
            const int b = (seg + 1) * 512;
            uint4* bh = (uint4*)(arena + (cur ^ 1) * 16384);
            uint4* bl = (uint4*)(arena + (cur ^ 1) * 16384 + 8192);
            stage16(gh4 + b + tid,       bh + tid);
            stage16(gh4 + b + 256 + tid, bh + 256 + tid);
            stage16(gl4 + b + tid,       bl + tid);
            stage16(gl4 + b + 256 + tid, bl + 256 + tid);
        }

        const unsigned short* shp =
            (const unsigned short*)(arena + cur * 16384);
        const unsigned short* slp = shp + 4096;     // +8192 B

#pragma unroll
        for (int s = 0; s < 4; ++s) {
            const bf16x8 bhi0 = ldbf8(shp + (s * 128 + lane) * 8);
            const bf16x8 bhi1 = ldbf8(shp + (s * 128 + 64 + lane) * 8);
            const bf16x8 blo0 = ldbf8(slp + (s * 128 + lane) * 8);
            const bf16x8 blo1 = ldbf8(slp + (s * 128 + 64 + lane) * 8);
            const float wqb = wsq_lds[seg * 64 + s * 16 + c16];
            const unsigned idx6 = (unsigned)(seg * 4 + s);   // wave-uniform

            // proven: two independent 3-chains, add at the end
            f32x4 a0 = {0.f, 0.f, 0.f, 0.f};
            f32x4 a1 = {0.f, 0.f, 0.f, 0.f};
            a0 = __builtin_amdgcn_mfma_f32_16x16x32_bf16(AL0, bhi0, a0, 0, 0, 0);
            a1 = __builtin_amdgcn_mfma_f32_16x16x32_bf16(AL1, bhi1, a1, 0, 0, 0);
            a0 = __builtin_amdgcn_mfma_f32_16x16x32_bf16(AH0, blo0, a0, 0, 0, 0);
            a1 = __builtin_amdgcn_mfma_f32_16x16x32_bf16(AH1, blo1, a1, 0, 0, 0);
            a0 = __builtin_amdgcn_mfma_f32_16x16x32_bf16(AH0, bhi0, a0, 0, 0, 0);
            a1 = __builtin_amdgcn_mfma_f32_16x16x32_bf16(AH1, bhi1, a1, 0, 0, 0);
#pragma unroll
            for (int i = 0; i < 4; ++i) {
                const float sc = fmaf(-2.0f, a0[i] + a1[i], wqb);  // biased, >0
                const unsigned p = (__float_as_uint(sc) & 0xFFFFFFC0u) | idx6;
                const unsigned mx = p > s1v[i] ? p : s1v[i];     // umax
                s2v[i] = s2v[i] < mx ? s2v[i] : mx;              // umin
                s1v[i] = s1v[i] < p  ? s1v[i] : p;               // umin
            }
        }
        __syncthreads();    // one barrier/seg: drains reads + next-seg DMA
    }
    // staging arena dead from here -> Mp1/Mp2 overlay is safe

    // ---- cross-residue merge (packed uints; proven semantics) ----
#pragma unroll
    for (int i = 0; i < 4; ++i) {
        Mp1[wave][quad * 4 + i][c16] = s1v[i];
        Mp2[wave][quad * 4 + i][c16] = s2v[i];
    }
    __syncthreads();
    if (tid < 64) {
        const int wv = tid >> 4, r = tid & 15;      // local row == tid
        unsigned g1 = 0xFFFFFFFFu, g2 = 0xFFFFFFFFu, g3 = 0xFFFFFFFFu;
        int gk1 = 0, gk2 = 0;
#pragma unroll
        for (int c = 0; c < 16; ++c) {
            {
                const unsigned p = Mp1[wv][r][c];
                if (p < g1)      { g3 = g2; g2 = g1; gk2 = gk1; g1 = p;
                                   gk1 = (int)(((p & 63u) << 4) | (unsigned)c); }
                else if (p < g2) { g3 = g2; g2 = p;
                                   gk2 = (int)(((p & 63u) << 4) | (unsigned)c); }
                else if (p < g3) { g3 = p; }
            }
            {
                const unsigned p = Mp2[wv][r][c];
                if (p < g1)      { g3 = g2; g2 = g1; gk2 = gk1; g1 = p;
                                   gk1 = (int)(((p & 63u) << 4) | (unsigned)c); }
                else if (p < g2) { g3 = g2; g2 = p;
                                   gk2 = (int)(((p & 63u) << 4) | (unsigned)c); }
                else if (p < g3) { g3 = p; }
            }
        }
        kf[tid] = gk1;
        const float f1 = __uint_as_float(g1 & 0xFFFFFFC0u);
        const float f2 = __uint_as_float(g2 & 0xFFFFFFC0u);
        const float f3 = __uint_as_float(g3 & 0xFFFFFFC0u);
        int st = 0;
        if (f2 - f1 <= MARGIN) st = (f3 - f1 > MARGIN) ? 1 : 2;
        strow[tid] = st;
        k2row[tid] = gk2;
    }
    __syncthreads();

    // ---- phase 1: pair rows (r10/r11-proven per-thread exact compare) ----
    if (tid < 64 && strow[tid] == 1) {
        const int row = blockIdx.x * 64 + tid;
        const int ka = kf[tid], kb = k2row[tid];
        const float4* xp = (const float4*)(x + (size_t)row * EMB_D);
        const float4* wa = (const float4*)(w + (size_t)ka * EMB_D);
        const float4* wb = (const float4*)(w + (size_t)kb * EMB_D);
        float r[8];
        double aa0 = 0, aa1 = 0, aa2 = 0, aa3 = 0;
        double ab0 = 0, ab1 = 0, ab2 = 0, ab3 = 0;
#pragma unroll
        for (int q = 0; q < 16; ++q) {
            const float4 xv = xp[q], va = wa[q], vb = wb[q];
            const int j = (q & 1) * 4;
            if (q < 2) {
                r[j + 0] = __fmul_rn(xv.x, xv.x);
                r[j + 1] = __fmul_rn(xv.y, xv.y);
                r[j + 2] = __fmul_rn(xv.z, xv.z);
                r[j + 3] = __fmul_rn(xv.w, xv.w);
            } else {
                r[j + 0] = __fadd_rn(r[j + 0], __fmul_rn(xv.x, xv.x));
                r[j + 1] = __fadd_rn(r[j + 1], __fmul_rn(xv.y, xv.y));
                r[j + 2] = __fadd_rn(r[j + 2], __fmul_rn(xv.z, xv.z));
                r[j + 3] = __fadd_rn(r[j + 3], __fmul_rn(xv.w, xv.w));
            }
            aa0 = fma((double)xv.x, (double)va.x, aa0);
            aa1 = fma((double)xv.y, (double)va.y, aa1);
            aa2 = fma((double)xv.z, (double)va.z, aa2);
            aa3 = fma((double)xv.w, (double)va.w, aa3);
            ab0 = fma((double)xv.x, (double)vb.x, ab0);
            ab1 = fma((double)xv.y, (double)vb.y, ab1);
            ab2 = fma((double)xv.z, (double)vb.z, ab2);
            ab3 = fma((double)xv.w, (double)vb.w, ab3);
        }
        const float xsq = __fadd_rn(
            __fadd_rn(__fadd_rn(r[0], r[1]), __fadd_rn(r[2], r[3])),
            __fadd_rn(__fadd_rn(r[4], r[5]), __fadd_rn(r[6], r[7])));
        const float mfa = (float)((aa0 + aa1) + (aa2 + aa3));
        const float mfb = (float)((ab0 + ab1) + (ab2 + ab3));
        const float sa = __fadd_rn(__fsub_rn(xsq, __fmul_rn(2.0f, mfa)), wsq[ka]);
        const float sb = __fadd_rn(__fsub_rn(xsq, __fmul_rn(2.0f, mfb)), wsq[kb]);
        int win = ka;
        if (sb < sa || (sb == sa && kb < ka)) win = kb;
        kf[tid] = win;
    }
    __syncthreads();

    // ---- phase 2: full rows (rare; r0-proven 4-wave cooperative body) ----
    __shared__ float4 xs4[16];
    __shared__ float  xsqs;
    __shared__ float  ls[256];
    __shared__ int    lk[256];
    for (int i = 0; i < 64; ++i) {
        if (strow[i] != 2) continue;                 // block-uniform (LDS)
        const int row = blockIdx.x * 64 + i;
        if (tid < 16) xs4[tid] = ((const float4*)(x + (size_t)row * EMB_D))[tid];
        __syncthreads();
        if (tid == 0) {
            const float* xf = (const float*)xs4;
            float r[8];
#pragma unroll
            for (int j = 0; j < 8; ++j) r[j] = __fmul_rn(xf[j], xf[j]);
#pragma unroll
            for (int t = 1; t < 8; ++t)
#pragma unroll
                for (int j = 0; j < 8; ++j)
                    r[j] = __fadd_rn(r[j], __fmul_rn(xf[t * 8 + j], xf[t * 8 + j]));
            xsqs = __fadd_rn(
                __fadd_rn(__fadd_rn(r[0], r[1]), __fadd_rn(r[2], r[3])),
                __fadd_rn(__fadd_rn(r[4], r[5]), __fadd_rn(r[6], r[7])));
        }
        __syncthreads();
        const float xsq = xsqs;

        float bs = INFINITY;
        int   bk = K;
        for (int t = 0; t < 4; ++t) {
            const int k = wave * (K >> 2) + t * 64 + lane;
            const float4* wr4 = (const float4*)(w + (size_t)k * EMB_D);
            double a0 = 0.0, a1 = 0.0, a2 = 0.0, a3 = 0.0;
#pragma unroll
            for (int q = 0; q < EMB_D / 4; ++q) {
                const float4 xv = xs4[q];
                const float4 wv = wr4[q];
                a0 = fma((double)xv.x, (double)wv.x, a0);
                a1 = fma((double)xv.y, (double)wv.y, a1);
                a2 = fma((double)xv.z, (double)wv.z, a2);
                a3 = fma((double)xv.w, (double)wv.w, a3);
            }
            const float mf = (float)((a0 + a1) + (a2 + a3));
            const float t2 = __fsub_rn(xsq, __fmul_rn(2.0f, mf));
            const float sc = __fadd_rn(t2, wsq[k]);
            if (sc < bs || (sc == bs && k < bk)) { bs = sc; bk = k; }
        }
        ls[tid] = bs; lk[tid] = bk;
        __syncthreads();
        if (wave == 0) {
            float gs = ls[lane];
            int   gk = lk[lane];
#pragma unroll
            for (int c = 1; c < 4; ++c) {
                const float os = ls[c * 64 + lane];
                const int   ok = lk[c * 64 + lane];
                if (os < gs || (os == gs && ok < gk)) { gs = os; gk = ok; }
            }
#pragma unroll
            for (int off = 32; off > 0; off >>= 1) {
                const float os = __shfl_down(gs, off);
                const int   ok = __shfl_down(gk, off);
                if (os < gs || (os == gs && ok < gk)) { gs = os; gk = ok; }
            }
            if (lane == 0) kf[i] = gk;
        }
        __syncthreads();
    }

    // ---- phase 3: indices + gather + loss (atomic accumulate) ----
    if (tid < 64) {
        const int row = blockIdx.x * 64 + tid;
        out[(size_t)N * EMB_D + row] = (float)kf[tid];
    }
    float lpart = 0.f;
#pragma unroll
    for (int rep = 0; rep < 4; ++rep) {
        int f4   = rep * 256 + tid;     // 0..1023
        int rr   = f4 >> 4;             // local row 0..63
        int c    = f4 & 15;
        int k    = kf[rr];
        int grow = blockIdx.x * 64 + rr;
        float4 wv = ((const float4*)(w + (size_t)k * EMB_D))[c];
        float4 xq = ((const float4*)(x + (size_t)grow * EMB_D))[c];
        ((float4*)out)[(size_t)grow * (EMB_D / 4) + c] = wv;
        float dx = wv.x - xq.x, dy = wv.y - xq.y;
        float dz = wv.z - xq.z, dw = wv.w - xq.w;
        lpart += dx * dx + dy * dy + dz * dz + dw * dw;
    }
#pragma unroll
    for (int off = 32; off > 0; off >>= 1) lpart += __shfl_down(lpart, off);
    __shared__ float lred[4];
    if (lane == 0) lred[wave] = lpart;
    __syncthreads();
    if (tid == 0)
        atomicAdd(loss_out, ((lred[0] + lred[1]) + (lred[2] + lred[3])) * scale);
}

extern "C" void kernel_launch(void* const* d_in, const int* in_sizes, int n_in,
                              void* d_out, int out_size, void* d_ws, size_t ws_size,
                              hipStream_t stream) {
    const float* x = (const float*)d_in[0];
    const float* w = (const float*)d_in[1];
    float* out = (float*)d_out;
    const int xsz = in_sizes[0];   // N * D
    const int wsz = in_sizes[1];   // K * D
    const int N   = xsz / EMB_D;   // 65536
    const int K   = wsz / EMB_D;   // 1024
    const int NB  = N / 64;        // 1024
    float* loss_out = out + (size_t)N * EMB_D + N;

    // ws: [wsq Kf][wt_hi K*64 u16][wt_lo K*64 u16]
    float* wsq = (float*)d_ws;
    unsigned short* wt_hi = (unsigned short*)(wsq + K);
    unsigned short* wt_lo = wt_hi + (size_t)K * EMB_D;

    vq_prepw_kernel<<<(K * 8 + 255) / 256, 256, 0, stream>>>(w, wt_hi, wt_lo,
                                                             wsq, loss_out, K);
    vq_fused_kernel<<<NB, 256, 0, stream>>>(x, wt_hi, wt_lo, wsq, w, out,
                                            loss_out, K, N,
                                            1.25f / (float)xsz);
}

// Round 10
// 138.936 us; speedup vs baseline: 1.0028x; 1.0028x over previous
//
#include <hip/hip_runtime.h>
#include <math.h>

#define EMB_D 64
// ref fp32-rounding band (~1.6e-5) + screen err (bf16-split ~6e-6 + 64-ULP
// pack-trunc ~3.8e-6 => ~1e-5 per score); need >= 3.6e-5, keep 6e-5 (1.7x slack)
#define MARGIN 6.0e-5f
// score bias: biased = 0.5 + (wsq - 2*x.w) in (0.3, 0.7), strictly positive
// => IEEE positive floats compare as uints.  (validated r2..r9: passed)
#define SBIAS 0.5f

typedef float  f32x4  __attribute__((ext_vector_type(4)));
typedef short  bf16x8 __attribute__((ext_vector_type(8)));

__device__ __forceinline__ unsigned short f2bf(float f) {
    unsigned int u = __float_as_uint(f);
    return (unsigned short)((u + 0x7FFFu + ((u >> 16) & 1u)) >> 16);
}
__device__ __forceinline__ float bf2f(unsigned short h) {
    return __uint_as_float(((unsigned int)h) << 16);
}

union Pack8 { ushort u[8]; bf16x8 v; uint4 q; };

// 16-B-aligned bf16x8 load (LDS or global) via uint4
__device__ __forceinline__ bf16x8 ldbf8(const unsigned short* p) {
    union { uint4 u; bf16x8 v; } c;
    c.u = *(const uint4*)p;
    return c.v;
}

// ---------------------------------------------------------------------------
// PREP-W: w -> bf16 hi/lo in MFMA-chunk-transposed order + wsq + zero loss.
// (unchanged, proven)
// ---------------------------------------------------------------------------
__global__ __launch_bounds__(256)
void vq_prepw_kernel(const float* __restrict__ w,
                     unsigned short* __restrict__ wt_hi,
                     unsigned short* __restrict__ wt_lo,
                     float* __restrict__ wsq, float* __restrict__ loss_out,
                     int K) {
    const int i = blockIdx.x * 256 + threadIdx.x;   // chunk id, K*8 total
    if (i == 0) loss_out[0] = 0.f;
    if (i >= K * 8) return;
    const int krow = i >> 3, q = i & 7;
    const int dest = ((krow >> 6) << 9) + (((krow >> 4) & 3) << 7) + (q << 4)
                   + (krow & 15);
    const float* src = w + (size_t)krow * EMB_D + q * 8;
    Pack8 h, l;
#pragma unroll
    for (int j = 0; j < 8; ++j) {
        const float f = src[j];
        h.u[j] = f2bf(f);
        l.u[j] = f2bf(f - bf2f(h.u[j]));
    }
    ((uint4*)wt_hi)[dest] = h.q;
    ((uint4*)wt_lo)[dest] = l.q;

    if (i < K) {   // wsq[i]: numpy-emulated fp32 sum(w_i^2)  [proven]
        const float* wr = w + (size_t)i * EMB_D;
        float r[8];
#pragma unroll
        for (int j = 0; j < 8; ++j) r[j] = __fmul_rn(wr[j], wr[j]);
#pragma unroll
        for (int t = 1; t < 8; ++t)
#pragma unroll
            for (int j = 0; j < 8; ++j)
                r[j] = __fadd_rn(r[j], __fmul_rn(wr[t * 8 + j], wr[t * 8 + j]));
        float a = __fadd_rn(__fadd_rn(r[0], r[1]), __fadd_rn(r[2], r[3]));
        float b = __fadd_rn(__fadd_rn(r[4], r[5]), __fadd_rn(r[6], r[7]));
        wsq[i] = __fadd_rn(a, b);
    }
}

// ---------------------------------------------------------------------------
// FUSED SCREEN + GATHER, v9 — K-half split (reuse WITHOUT losing TLP):
//  - v8 post-mortem: DMA restage null (77.6 vs v7 73.4) -> revert to v7's
//    reg-staged loop.  10-round data: main ~51us in every geometry; LDS-read
//    redundancy (4 waves x same B-frags) is the largest pipe cost, but v4's
//    2-tile fix halved wave count (8/CU) and broke even.
//  - v9: wave (h = wave>>1, rg = wave&1) handles rows rg*32..+32 (2 tiles)
//    x codes h*512..+512.  Block still 64 rows x 1024 codes, grid 1024 ->
//    16 waves/CU (v7 TLP) with HALF the per-wave B-frag LDS reads (v4 reuse).
//  - staging granularity: 32-code segs, 16KB/iter = 4 uint4/thread (v7's
//    proven no-spill width); chunk layout is linear in 32-code units.
//  - scores bit-identical to v7 (same MFMA order per candidate); merge
//    takes candidates from 2 waves per row (order-safe, ties unchanged).
//  - selection/tail: proven (absmax 3.8e-6 across r2..r9).
// ---------------------------------------------------------------------------
__global__ __launch_bounds__(256, 2)
void vq_fused_kernel(const float* __restrict__ x,
                     const unsigned short* __restrict__ wt_hi,
                     const unsigned short* __restrict__ wt_lo,
                     const float* __restrict__ wsq,
                     const float* __restrict__ w,
                     float* __restrict__ out, float* __restrict__ loss_out,
                     int K, int N, float scale) {
    const int tid  = threadIdx.x;       // 0..255
    const int lane = tid & 63;
    const int wave = tid >> 6;          // 0..3
    const int quad = lane >> 4;
    const int c16  = lane & 15;
    const int h    = wave >> 1;         // K-half: codes h*512..+512
    const int rg   = wave & 1;          // row-group: rows rg*32..+32
    const int rowbase = blockIdx.x * 64 + rg * 32;   // tiles at +0, +16

    // arena: staging 16KB (h0hi 4K | h0lo 4K | h1hi 4K | h1lo 4K) during the
    // seg loop; Mp1/Mp2 packed-merge overlay (2x8704B) after it.
    __shared__ __align__(16) char arena[17408];
    __shared__ float wsq_lds[1024];         // biased: wsq + SBIAS (4 KB)
    typedef unsigned MpArr[32][17];         // [4 waves][32 rows-in-group][pad]
    MpArr* Mp1 = (MpArr*)arena;             // 8704 B (after seg loop)
    MpArr* Mp2 = (MpArr*)(arena + 8704);    // 8704 B
    __shared__ int kf[64], strow[64], k2row[64];

    // ---- A-frags: split x hi/lo in-register for both 16-row tiles ----
    Pack8 AH0[2], AL0[2], AH1[2], AL1[2];
#pragma unroll
    for (int tt = 0; tt < 2; ++tt) {
        const float* xrow =
            x + (size_t)(rowbase + tt * 16 + c16) * EMB_D + quad * 8;
#pragma unroll
        for (int j = 0; j < 8; ++j) {
            const float f0 = xrow[j];
            AH0[tt].u[j] = f2bf(f0);
            AL0[tt].u[j] = f2bf(f0 - bf2f(AH0[tt].u[j]));
            const float f1 = xrow[32 + j];
            AH1[tt].u[j] = f2bf(f1);
            AL1[tt].u[j] = f2bf(f1 - bf2f(AH1[tt].u[j]));
        }
    }

    {   // biased wsq into LDS (global wsq stays unbiased for exact paths)
        float4 a = ((const float4*)wsq)[tid];
        a.x += SBIAS; a.y += SBIAS; a.z += SBIAS; a.w += SBIAS;
        ((float4*)wsq_lds)[tid] = a;
    }

    // packed top-2 per (tile, acc-row)
    unsigned s1v[2][4], s2v[2][4];
#pragma unroll
    for (int tt = 0; tt < 2; ++tt)
#pragma unroll
        for (int i = 0; i < 4; ++i) { s1v[tt][i] = 0xFFFFFFFFu; s2v[tt][i] = 0xFFFFFFFFu; }

    const uint4* gh4 = (const uint4*)wt_hi;
    const uint4* gl4 = (const uint4*)wt_lo;
    // prefetch iter 0: h0 seg 0 (chunks 0..255), h1 seg 16 (chunks 4096..)
    uint4 ph0 = gh4[tid], pl0 = gl4[tid];
    uint4 ph1 = gh4[4096 + tid], pl1 = gl4[4096 + tid];

    for (int t = 0; t < 16; ++t) {      // 16 iters of 32 codes per half
        ((uint4*)arena)[tid]           = ph0;   // h0 hi
        ((uint4*)(arena + 4096))[tid]  = pl0;   // h0 lo
        ((uint4*)(arena + 8192))[tid]  = ph1;   // h1 hi
        ((uint4*)(arena + 12288))[tid] = pl1;   // h1 lo
        __syncthreads();
        if (t + 1 < 16) {               // prefetch next iter (coalesced)
            ph0 = gh4[(t + 1) * 256 + tid];
            pl0 = gl4[(t + 1) * 256 + tid];
            ph1 = gh4[(17 + t) * 256 + tid];
            pl1 = gl4[(17 + t) * 256 + tid];
        }

        const unsigned short* shp =
            (const unsigned short*)(arena + h * 8192);
        const unsigned short* slp = shp + 2048;     // +4096 B

#pragma unroll
        for (int s = 0; s < 2; ++s) {   // 16-code subtiles of this 32-code seg
            const bf16x8 bhi0 = ldbf8(shp + (s * 128 + lane) * 8);
            const bf16x8 bhi1 = ldbf8(shp + (s * 128 + 64 + lane) * 8);
            const bf16x8 blo0 = ldbf8(slp + (s * 128 + lane) * 8);
            const bf16x8 blo1 = ldbf8(slp + (s * 128 + 64 + lane) * 8);
            const unsigned u = (unsigned)(h * 32 + t * 2 + s);  // global idx6
            const float wqb = wsq_lds[u * 16 + c16];

#pragma unroll
            for (int tt = 0; tt < 2; ++tt) {
                // proven: two independent 3-chains, add at the end
                f32x4 a0 = {0.f, 0.f, 0.f, 0.f};
                f32x4 a1 = {0.f, 0.f, 0.f, 0.f};
                a0 = __builtin_amdgcn_mfma_f32_16x16x32_bf16(AL0[tt].v, bhi0, a0, 0, 0, 0);
                a1 = __builtin_amdgcn_mfma_f32_16x16x32_bf16(AL1[tt].v, bhi1, a1, 0, 0, 0);
                a0 = __builtin_amdgcn_mfma_f32_16x16x32_bf16(AH0[tt].v, blo0, a0, 0, 0, 0);
                a1 = __builtin_amdgcn_mfma_f32_16x16x32_bf16(AH1[tt].v, blo1, a1, 0, 0, 0);
                a0 = __builtin_amdgcn_mfma_f32_16x16x32_bf16(AH0[tt].v, bhi0, a0, 0, 0, 0);
                a1 = __builtin_amdgcn_mfma_f32_16x16x32_bf16(AH1[tt].v, bhi1, a1, 0, 0, 0);
#pragma unroll
                for (int i = 0; i < 4; ++i) {
                    const float sc = fmaf(-2.0f, a0[i] + a1[i], wqb);  // >0
                    const unsigned p = (__float_as_uint(sc) & 0xFFFFFFC0u) | u;
                    const unsigned mx = p > s1v[tt][i] ? p : s1v[tt][i];  // umax
                    s2v[tt][i] = s2v[tt][i] < mx ? s2v[tt][i] : mx;       // umin
                    s1v[tt][i] = s1v[tt][i] < p  ? s1v[tt][i] : p;        // umin
                }
            }
        }
        __syncthreads();
    }
    // staging arena dead from here -> Mp1/Mp2 overlay is safe

    // ---- cross-residue + cross-half merge (packed uints) ----
#pragma unroll
    for (int tt = 0; tt < 2; ++tt)
#pragma unroll
        for (int i = 0; i < 4; ++i) {
            const int rr = tt * 16 + quad * 4 + i;   // row within group
            Mp1[wave][rr][c16] = s1v[tt][i];
            Mp2[wave][rr][c16] = s2v[tt][i];
        }
    __syncthreads();
    if (tid < 64) {
        const int rg2 = tid >> 5, rr = tid & 31;    // local row == tid
        unsigned g1 = 0xFFFFFFFFu, g2 = 0xFFFFFFFFu, g3 = 0xFFFFFFFFu;
        int gk1 = 0, gk2 = 0;
#pragma unroll
        for (int c = 0; c < 16; ++c) {
#pragma unroll
            for (int j = 0; j < 2; ++j) {           // the row's 2 waves (halves)
                const int wv = rg2 + j * 2;
                {
                    const unsigned p = Mp1[wv][rr][c];
                    if (p < g1)      { g3 = g2; g2 = g1; gk2 = gk1; g1 = p;
                                       gk1 = (int)(((p & 63u) << 4) | (unsigned)c); }
                    else if (p < g2) { g3 = g2; g2 = p;
                                       gk2 = (int)(((p & 63u) << 4) | (unsigned)c); }
                    else if (p < g3) { g3 = p; }
                }
                {
                    const unsigned p = Mp2[wv][rr][c];
                    if (p < g1)      { g3 = g2; g2 = g1; gk2 = gk1; g1 = p;
                                       gk1 = (int)(((p & 63u) << 4) | (unsigned)c); }
                    else if (p < g2) { g3 = g2; g2 = p;
                                       gk2 = (int)(((p & 63u) << 4) | (unsigned)c); }
                    else if (p < g3) { g3 = p; }
                }
            }
        }
        kf[tid] = gk1;
        const float f1 = __uint_as_float(g1 & 0xFFFFFFC0u);
        const float f2 = __uint_as_float(g2 & 0xFFFFFFC0u);
        const float f3 = __uint_as_float(g3 & 0xFFFFFFC0u);
        int st = 0;
        if (f2 - f1 <= MARGIN) st = (f3 - f1 > MARGIN) ? 1 : 2;
        strow[tid] = st;
        k2row[tid] = gk2;
    }
    __syncthreads();

    // ---- phase 1: pair rows (r10/r11-proven per-thread exact compare) ----
    if (tid < 64 && strow[tid] == 1) {
        const int row = blockIdx.x * 64 + tid;
        const int ka = kf[tid], kb = k2row[tid];
        const float4* xp = (const float4*)(x + (size_t)row * EMB_D);
        const float4* wa = (const float4*)(w + (size_t)ka * EMB_D);
        const float4* wb = (const float4*)(w + (size_t)kb * EMB_D);
        float r[8];
        double aa0 = 0, aa1 = 0, aa2 = 0, aa3 = 0;
        double ab0 = 0, ab1 = 0, ab2 = 0, ab3 = 0;
#pragma unroll
        for (int q = 0; q < 16; ++q) {
            const float4 xv = xp[q], va = wa[q], vb = wb[q];
            const int j = (q & 1) * 4;
            if (q < 2) {
                r[j + 0] = __fmul_rn(xv.x, xv.x);
                r[j + 1] = __fmul_rn(xv.y, xv.y);
                r[j + 2] = __fmul_rn(xv.z, xv.z);
                r[j + 3] = __fmul_rn(xv.w, xv.w);
            } else {
                r[j + 0] = __fadd_rn(r[j + 0], __fmul_rn(xv.x, xv.x));
                r[j + 1] = __fadd_rn(r[j + 1], __fmul_rn(xv.y, xv.y));
                r[j + 2] = __fadd_rn(r[j + 2], __fmul_rn(xv.z, xv.z));
                r[j + 3] = __fadd_rn(r[j + 3], __fmul_rn(xv.w, xv.w));
            }
            aa0 = fma((double)xv.x, (double)va.x, aa0);
            aa1 = fma((double)xv.y, (double)va.y, aa1);
            aa2 = fma((double)xv.z, (double)va.z, aa2);
            aa3 = fma((double)xv.w, (double)va.w, aa3);
            ab0 = fma((double)xv.x, (double)vb.x, ab0);
            ab1 = fma((double)xv.y, (double)vb.y, ab1);
            ab2 = fma((double)xv.z, (double)vb.z, ab2);
            ab3 = fma((double)xv.w, (double)vb.w, ab3);
        }
        const float xsq = __fadd_rn(
            __fadd_rn(__fadd_rn(r[0], r[1]), __fadd_rn(r[2], r[3])),
            __fadd_rn(__fadd_rn(r[4], r[5]), __fadd_rn(r[6], r[7])));
        const float mfa = (float)((aa0 + aa1) + (aa2 + aa3));
        const float mfb = (float)((ab0 + ab1) + (ab2 + ab3));
        const float sa = __fadd_rn(__fsub_rn(xsq, __fmul_rn(2.0f, mfa)), wsq[ka]);
        const float sb = __fadd_rn(__fsub_rn(xsq, __fmul_rn(2.0f, mfb)), wsq[kb]);
        int win = ka;
        if (sb < sa || (sb == sa && kb < ka)) win = kb;
        kf[tid] = win;
    }
    __syncthreads();

    // ---- phase 2: full rows (rare; r0-proven 4-wave cooperative body) ----
    __shared__ float4 xs4[16];
    __shared__ float  xsqs;
    __shared__ float  ls[256];
    __shared__ int    lk[256];
    for (int i = 0; i < 64; ++i) {
        if (strow[i] != 2) continue;                 // block-uniform (LDS)
        const int row = blockIdx.x * 64 + i;
        if (tid < 16) xs4[tid] = ((const float4*)(x + (size_t)row * EMB_D))[tid];
        __syncthreads();
        if (tid == 0) {
            const float* xf = (const float*)xs4;
            float r[8];
#pragma unroll
            for (int j = 0; j < 8; ++j) r[j] = __fmul_rn(xf[j], xf[j]);
#pragma unroll
            for (int t = 1; t < 8; ++t)
#pragma unroll
                for (int j = 0; j < 8; ++j)
                    r[j] = __fadd_rn(r[j], __fmul_rn(xf[t * 8 + j], xf[t * 8 + j]));
            xsqs = __fadd_rn(
                __fadd_rn(__fadd_rn(r[0], r[1]), __fadd_rn(r[2], r[3])),
                __fadd_rn(__fadd_rn(r[4], r[5]), __fadd_rn(r[6], r[7])));
        }
        __syncthreads();
        const float xsq = xsqs;

        float bs = INFINITY;
        int   bk = K;
        for (int t = 0; t < 4; ++t) {
            const int k = wave * (K >> 2) + t * 64 + lane;
            const float4* wr4 = (const float4*)(w + (size_t)k * EMB_D);
            double a0 = 0.0, a1 = 0.0, a2 = 0.0, a3 = 0.0;
#pragma unroll
            for (int q = 0; q < EMB_D / 4; ++q) {
                const float4 xv = xs4[q];
                const float4 wv = wr4[q];
                a0 = fma((double)xv.x, (double)wv.x, a0);
                a1 = fma((double)xv.y, (double)wv.y, a1);
                a2 = fma((double)xv.z, (double)wv.z, a2);
                a3 = fma((double)xv.w, (double)wv.w, a3);
            }
            const float mf = (float)((a0 + a1) + (a2 + a3));
            const float t2 = __fsub_rn(xsq, __fmul_rn(2.0f, mf));
            const float sc = __fadd_rn(t2, wsq[k]);
            if (sc < bs || (sc == bs && k < bk)) { bs = sc; bk = k; }
        }
        ls[tid] = bs; lk[tid] = bk;
        __syncthreads();
        if (wave == 0) {
            float gs = ls[lane];
            int   gk = lk[lane];
#pragma unroll
            for (int c = 1; c < 4; ++c) {
                const float os = ls[c * 64 + lane];
                const int   ok = lk[c * 64 + lane];
                if (os < gs || (os == gs && ok < gk)) { gs = os; gk = ok; }
            }
#pragma unroll
            for (int off = 32; off > 0; off >>= 1) {
                const float os = __shfl_down(gs, off);
                const int   ok = __shfl_down(gk, off);
                if (os < gs || (os == gs && ok < gk)) { gs = os; gk = ok; }
            }
            if (lane == 0) kf[i] = gk;
        }
        __syncthreads();
    }

    // ---- phase 3: indices + gather + loss (atomic accumulate) ----
    if (tid < 64) {
        const int row = blockIdx.x * 64 + tid;
        out[(size_t)N * EMB_D + row] = (float)kf[tid];
    }
    float lpart = 0.f;
#pragma unroll
    for (int rep = 0; rep < 4; ++rep) {
        int f4   = rep * 256 + tid;     // 0..1023
        int rr   = f4 >> 4;             // local row 0..63
        int c    = f4 & 15;
        int k    = kf[rr];
        int grow = blockIdx.x * 64 + rr;
        float4 wv = ((const float4*)(w + (size_t)k * EMB_D))[c];
        float4 xq = ((const float4*)(x + (size_t)grow * EMB_D))[c];
        ((float4*)out)[(size_t)grow * (EMB_D / 4) + c] = wv;
        float dx = wv.x - xq.x, dy = wv.y - xq.y;
        float dz = wv.z - xq.z, dw = wv.w - xq.w;
        lpart += dx * dx + dy * dy + dz * dz + dw * dw;
    }
#pragma unroll
    for (int off = 32; off > 0; off >>= 1) lpart += __shfl_down(lpart, off);
    __shared__ float lred[4];
    if (lane == 0) lred[wave] = lpart;
    __syncthreads();
    if (tid == 0)
        atomicAdd(loss_out, ((lred[0] + lred[1]) + (lred[2] + lred[3])) * scale);
}

extern "C" void kernel_launch(void* const* d_in, const int* in_sizes, int n_in,
                              void* d_out, int out_size, void* d_ws, size_t ws_size,
                              hipStream_t stream) {
    const float* x = (const float*)d_in[0];
    const float* w = (const float*)d_in[1];
    float* out = (float*)d_out;
    const int xsz = in_sizes[0];   // N * D
    const int wsz = in_sizes[1];   // K * D
    const int N   = xsz / EMB_D;   // 65536
    const int K   = wsz / EMB_D;   // 1024
    const int NB  = N / 64;        // 1024
    float* loss_out = out + (size_t)N * EMB_D + N;

    // ws: [wsq Kf][wt_hi K*64 u16][wt_lo K*64 u16]
    float* wsq = (float*)d_ws;
    unsigned short* wt_hi = (unsigned short*)(wsq + K);
    unsigned short* wt_lo = wt_hi + (size_t)K * EMB_D;

    vq_prepw_kernel<<<(K * 8 + 255) / 256, 256, 0, stream>>>(w, wt_hi, wt_lo,
                                                             wsq, loss_out, K);
    vq_fused_kernel<<<NB, 256, 0, stream>>>(x, wt_hi, wt_lo, wsq, w, out,
                                            loss_out, K, N,
                                            1.25f / (float)xsz);
}

// Round 11
// 133.476 us; speedup vs baseline: 1.0438x; 1.0409x over previous
//
#include <hip/hip_runtime.h>
#include <math.h>

#define EMB_D 64
// ref fp32-rounding band (~1.6e-5) + screen err (bf16-split ~6e-6 + 64-ULP
// pack-trunc ~3.8e-6 => ~1e-5 per score); need >= 3.6e-5, keep 6e-5 (1.7x slack)
#define MARGIN 6.0e-5f
// score bias: biased = 0.5 + (wsq - 2*x.w) in (0.3, 0.7), strictly positive
// => IEEE positive floats compare as uints.  (validated r2..r10: passed)
#define SBIAS 0.5f

typedef float  f32x4  __attribute__((ext_vector_type(4)));
typedef short  bf16x8 __attribute__((ext_vector_type(8)));

__device__ __forceinline__ unsigned short f2bf(float f) {
    unsigned int u = __float_as_uint(f);
    return (unsigned short)((u + 0x7FFFu + ((u >> 16) & 1u)) >> 16);
}
__device__ __forceinline__ float bf2f(unsigned short h) {
    return __uint_as_float(((unsigned int)h) << 16);
}

union Pack8 { ushort u[8]; bf16x8 v; uint4 q; };

// 16-B-aligned bf16x8 load (LDS or global) via uint4
__device__ __forceinline__ bf16x8 ldbf8(const unsigned short* p) {
    union { uint4 u; bf16x8 v; } c;
    c.u = *(const uint4*)p;
    return c.v;
}

// ---------------------------------------------------------------------------
// PREP-W: w -> bf16 hi/lo in MFMA-chunk-transposed order + wsq + zero loss.
// (unchanged, proven)
// ---------------------------------------------------------------------------
__global__ __launch_bounds__(256)
void vq_prepw_kernel(const float* __restrict__ w,
                     unsigned short* __restrict__ wt_hi,
                     unsigned short* __restrict__ wt_lo,
                     float* __restrict__ wsq, float* __restrict__ loss_out,
                     int K) {
    const int i = blockIdx.x * 256 + threadIdx.x;   // chunk id, K*8 total
    if (i == 0) loss_out[0] = 0.f;
    if (i >= K * 8) return;
    const int krow = i >> 3, q = i & 7;
    const int dest = ((krow >> 6) << 9) + (((krow >> 4) & 3) << 7) + (q << 4)
                   + (krow & 15);
    const float* src = w + (size_t)krow * EMB_D + q * 8;
    Pack8 h, l;
#pragma unroll
    for (int j = 0; j < 8; ++j) {
        const float f = src[j];
        h.u[j] = f2bf(f);
        l.u[j] = f2bf(f - bf2f(h.u[j]));
    }
    ((uint4*)wt_hi)[dest] = h.q;
    ((uint4*)wt_lo)[dest] = l.q;

    if (i < K) {   // wsq[i]: numpy-emulated fp32 sum(w_i^2)  [proven]
        const float* wr = w + (size_t)i * EMB_D;
        float r[8];
#pragma unroll
        for (int j = 0; j < 8; ++j) r[j] = __fmul_rn(wr[j], wr[j]);
#pragma unroll
        for (int t = 1; t < 8; ++t)
#pragma unroll
            for (int j = 0; j < 8; ++j)
                r[j] = __fadd_rn(r[j], __fmul_rn(wr[t * 8 + j], wr[t * 8 + j]));
        float a = __fadd_rn(__fadd_rn(r[0], r[1]), __fadd_rn(r[2], r[3]));
        float b = __fadd_rn(__fadd_rn(r[4], r[5]), __fadd_rn(r[6], r[7]));
        wsq[i] = __fadd_rn(a, b);
    }
}

// ---------------------------------------------------------------------------
// FUSED SCREEN + GATHER, v10 = v7 with single-barrier double-buffered staging
// (guide T3 "minimum 2-phase"):
//  - r2..r10 data: every reuse/TLP/DMA/global-direct variant lands 50-80us
//    main loop with ALL pipes <25% -> the residual is the 2-barrier-per-seg
//    schedule (32 full vmcnt+lgkm drains where all waves collapse).
//  - v10: iter t = { ds_write regs->buf[cur^1]; global_load regs<-seg t+2;
//    compute buf[cur]; barrier }.  Barrier at end of t-1 retired all reads
//    of buf[cur^1], so overlapped writes are race-free; ONE barrier per seg
//    gives both WAR protection and visibility.  Barriers 32 -> 17; staging
//    writes overlap compute instead of being drain-fenced.
//  - prefetch state stays 16 VGPR (v7's proven no-spill width);
//    launch_bounds (256,2) per r7's spill finding.
//  - Mp1/Mp2 merge arrays overlay the dead staging arena after final barrier.
//  - selection/tail: v7 verbatim (proven, absmax 3.8e-6 across r2..r10).
// ---------------------------------------------------------------------------
__global__ __launch_bounds__(256, 2)
void vq_fused_kernel(const float* __restrict__ x,
                     const unsigned short* __restrict__ wt_hi,
                     const unsigned short* __restrict__ wt_lo,
                     const float* __restrict__ wsq,
                     const float* __restrict__ w,
                     float* __restrict__ out, float* __restrict__ loss_out,
                     int K, int N, float scale) {
    const int tid  = threadIdx.x;       // 0..255
    const int lane = tid & 63;
    const int wave = tid >> 6;          // 0..3
    const int quad = lane >> 4;
    const int c16  = lane & 15;
    const int rowbase = blockIdx.x * 64 + wave * 16;

    // staging arena: buf b at arena+b*16384 (hi 8KB | lo 8KB)
    __shared__ __align__(16) char arena[32768];
    __shared__ float wsq_lds[1024];         // biased: wsq + SBIAS (4 KB)
    typedef unsigned MpArr[16][17];         // merge overlay (after seg loop)
    MpArr* Mp1 = (MpArr*)arena;             // 4x16x17x4 = 4352 B
    MpArr* Mp2 = (MpArr*)(arena + 4352);    // 4352 B
    __shared__ int kf[64], strow[64], k2row[64];

    const uint4* gh4 = (const uint4*)wt_hi;
    const uint4* gl4 = (const uint4*)wt_lo;

    // ---- prologue: seg0 -> buf0 (through regs), then load seg1 regs ----
    uint4 ph0 = gh4[tid], ph1 = gh4[256 + tid];
    uint4 pl0 = gl4[tid], pl1 = gl4[256 + tid];
    {
        uint4* bh = (uint4*)arena;
        uint4* bl = (uint4*)(arena + 8192);
        bh[tid] = ph0; bh[256 + tid] = ph1;
        bl[tid] = pl0; bl[256 + tid] = pl1;
    }
    ph0 = gh4[512 + tid]; ph1 = gh4[768 + tid];     // seg1
    pl0 = gl4[512 + tid]; pl1 = gl4[768 + tid];

    // ---- A-frags: split x hi/lo in-register (this lane's 16 floats) ----
    const float* xrow = x + (size_t)(rowbase + c16) * EMB_D + quad * 8;
    Pack8 ah0, al0, ah1, al1;
#pragma unroll
    for (int j = 0; j < 8; ++j) {
        const float f0 = xrow[j];
        ah0.u[j] = f2bf(f0); al0.u[j] = f2bf(f0 - bf2f(ah0.u[j]));
        const float f1 = xrow[32 + j];
        ah1.u[j] = f2bf(f1); al1.u[j] = f2bf(f1 - bf2f(ah1.u[j]));
    }
    const bf16x8 AH0 = ah0.v, AL0 = al0.v, AH1 = ah1.v, AL1 = al1.v;

    {   // biased wsq into LDS (global wsq stays unbiased for exact paths)
        float4 a = ((const float4*)wsq)[tid];
        a.x += SBIAS; a.y += SBIAS; a.z += SBIAS; a.w += SBIAS;
        ((float4*)wsq_lds)[tid] = a;
    }

    // packed top-2 per acc-row
    unsigned s1v[4], s2v[4];
#pragma unroll
    for (int i = 0; i < 4; ++i) { s1v[i] = 0xFFFFFFFFu; s2v[i] = 0xFFFFFFFFu; }

    __syncthreads();                    // buf0 writes visible

    const int nseg = K >> 6;            // 16
    for (int seg = 0; seg < nseg; ++seg) {
        const int cur = seg & 1;
        if (seg + 1 < nseg) {           // write seg+1 (in regs) to other buf
            uint4* bh = (uint4*)(arena + (cur ^ 1) * 16384);
            uint4* bl = (uint4*)(arena + (cur ^ 1) * 16384 + 8192);
            bh[tid] = ph0; bh[256 + tid] = ph1;
            bl[tid] = pl0; bl[256 + tid] = pl1;
            if (seg + 2 < nseg) {       // load seg+2 into regs (coalesced)
                const int b = (seg + 2) * 512;
                ph0 = gh4[b + tid]; ph1 = gh4[b + 256 + tid];
                pl0 = gl4[b + tid]; pl1 = gl4[b + 256 + tid];
            }
        }

        const unsigned short* shp =
            (const unsigned short*)(arena + cur * 16384);
        const unsigned short* slp = shp + 4096;     // +8192 B

#pragma unroll
        for (int s = 0; s < 4; ++s) {
            const bf16x8 bhi0 = ldbf8(shp + (s * 128 + lane) * 8);
            const bf16x8 bhi1 = ldbf8(shp + (s * 128 + 64 + lane) * 8);
            const bf16x8 blo0 = ldbf8(slp + (s * 128 + lane) * 8);
            const bf16x8 blo1 = ldbf8(slp + (s * 128 + 64 + lane) * 8);
            const float wqb = wsq_lds[seg * 64 + s * 16 + c16];
            const unsigned idx6 = (unsigned)(seg * 4 + s);   // wave-uniform

            // proven: two independent 3-chains, add at the end
            f32x4 a0 = {0.f, 0.f, 0.f, 0.f};
            f32x4 a1 = {0.f, 0.f, 0.f, 0.f};
            a0 = __builtin_amdgcn_mfma_f32_16x16x32_bf16(AL0, bhi0, a0, 0, 0, 0);
            a1 = __builtin_amdgcn_mfma_f32_16x16x32_bf16(AL1, bhi1, a1, 0, 0, 0);
            a0 = __builtin_amdgcn_mfma_f32_16x16x32_bf16(AH0, blo0, a0, 0, 0, 0);
            a1 = __builtin_amdgcn_mfma_f32_16x16x32_bf16(AH1, blo1, a1, 0, 0, 0);
            a0 = __builtin_amdgcn_mfma_f32_16x16x32_bf16(AH0, bhi0, a0, 0, 0, 0);
            a1 = __builtin_amdgcn_mfma_f32_16x16x32_bf16(AH1, bhi1, a1, 0, 0, 0);
#pragma unroll
            for (int i = 0; i < 4; ++i) {
                const float sc = fmaf(-2.0f, a0[i] + a1[i], wqb);  // biased, >0
                const unsigned p = (__float_as_uint(sc) & 0xFFFFFFC0u) | idx6;
                const unsigned mx = p > s1v[i] ? p : s1v[i];     // umax
                s2v[i] = s2v[i] < mx ? s2v[i] : mx;              // umin
                s1v[i] = s1v[i] < p  ? s1v[i] : p;               // umin
            }
        }
        __syncthreads();    // ONE barrier/seg: visibility + WAR for both bufs
    }
    // staging arena dead from here -> Mp1/Mp2 overlay is safe

    // ---- cross-residue merge (packed uints; proven semantics) ----
#pragma unroll
    for (int i = 0; i < 4; ++i) {
        Mp1[wave][quad * 4 + i][c16] = s1v[i];
        Mp2[wave][quad * 4 + i][c16] = s2v[i];
    }
    __syncthreads();
    if (tid < 64) {
        const int wv = tid >> 4, r = tid & 15;      // local row == tid
        unsigned g1 = 0xFFFFFFFFu, g2 = 0xFFFFFFFFu, g3 = 0xFFFFFFFFu;
        int gk1 = 0, gk2 = 0;
#pragma unroll
        for (int c = 0; c < 16; ++c) {
            {
                const unsigned p = Mp1[wv][r][c];
                if (p < g1)      { g3 = g2; g2 = g1; gk2 = gk1; g1 = p;
                                   gk1 = (int)(((p & 63u) << 4) | (unsigned)c); }
                else if (p < g2) { g3 = g2; g2 = p;
                                   gk2 = (int)(((p & 63u) << 4) | (unsigned)c); }
                else if (p < g3) { g3 = p; }
            }
            {
                const unsigned p = Mp2[wv][r][c];
                if (p < g1)      { g3 = g2; g2 = g1; gk2 = gk1; g1 = p;
                                   gk1 = (int)(((p & 63u) << 4) | (unsigned)c); }
                else if (p < g2) { g3 = g2; g2 = p;
                                   gk2 = (int)(((p & 63u) << 4) | (unsigned)c); }
                else if (p < g3) { g3 = p; }
            }
        }
        kf[tid] = gk1;
        const float f1 = __uint_as_float(g1 & 0xFFFFFFC0u);
        const float f2 = __uint_as_float(g2 & 0xFFFFFFC0u);
        const float f3 = __uint_as_float(g3 & 0xFFFFFFC0u);
        int st = 0;
        if (f2 - f1 <= MARGIN) st = (f3 - f1 > MARGIN) ? 1 : 2;
        strow[tid] = st;
        k2row[tid] = gk2;
    }
    __syncthreads();

    // ---- phase 1: pair rows (r10/r11-proven per-thread exact compare) ----
    if (tid < 64 && strow[tid] == 1) {
        const int row = blockIdx.x * 64 + tid;
        const int ka = kf[tid], kb = k2row[tid];
        const float4* xp = (const float4*)(x + (size_t)row * EMB_D);
        const float4* wa = (const float4*)(w + (size_t)ka * EMB_D);
        const float4* wb = (const float4*)(w + (size_t)kb * EMB_D);
        float r[8];
        double aa0 = 0, aa1 = 0, aa2 = 0, aa3 = 0;
        double ab0 = 0, ab1 = 0, ab2 = 0, ab3 = 0;
#pragma unroll
        for (int q = 0; q < 16; ++q) {
            const float4 xv = xp[q], va = wa[q], vb = wb[q];
            const int j = (q & 1) * 4;
            if (q < 2) {
                r[j + 0] = __fmul_rn(xv.x, xv.x);
                r[j + 1] = __fmul_rn(xv.y, xv.y);
                r[j + 2] = __fmul_rn(xv.z, xv.z);
                r[j + 3] = __fmul_rn(xv.w, xv.w);
            } else {
                r[j + 0] = __fadd_rn(r[j + 0], __fmul_rn(xv.x, xv.x));
                r[j + 1] = __fadd_rn(r[j + 1], __fmul_rn(xv.y, xv.y));
                r[j + 2] = __fadd_rn(r[j + 2], __fmul_rn(xv.z, xv.z));
                r[j + 3] = __fadd_rn(r[j + 3], __fmul_rn(xv.w, xv.w));
            }
            aa0 = fma((double)xv.x, (double)va.x, aa0);
            aa1 = fma((double)xv.y, (double)va.y, aa1);
            aa2 = fma((double)xv.z, (double)va.z, aa2);
            aa3 = fma((double)xv.w, (double)va.w, aa3);
            ab0 = fma((double)xv.x, (double)vb.x, ab0);
            ab1 = fma((double)xv.y, (double)vb.y, ab1);
            ab2 = fma((double)xv.z, (double)vb.z, ab2);
            ab3 = fma((double)xv.w, (double)vb.w, ab3);
        }
        const float xsq = __fadd_rn(
            __fadd_rn(__fadd_rn(r[0], r[1]), __fadd_rn(r[2], r[3])),
            __fadd_rn(__fadd_rn(r[4], r[5]), __fadd_rn(r[6], r[7])));
        const float mfa = (float)((aa0 + aa1) + (aa2 + aa3));
        const float mfb = (float)((ab0 + ab1) + (ab2 + ab3));
        const float sa = __fadd_rn(__fsub_rn(xsq, __fmul_rn(2.0f, mfa)), wsq[ka]);
        const float sb = __fadd_rn(__fsub_rn(xsq, __fmul_rn(2.0f, mfb)), wsq[kb]);
        int win = ka;
        if (sb < sa || (sb == sa && kb < ka)) win = kb;
        kf[tid] = win;
    }
    __syncthreads();

    // ---- phase 2: full rows (rare; r0-proven 4-wave cooperative body) ----
    __shared__ float4 xs4[16];
    __shared__ float  xsqs;
    __shared__ float  ls[256];
    __shared__ int    lk[256];
    for (int i = 0; i < 64; ++i) {
        if (strow[i] != 2) continue;                 // block-uniform (LDS)
        const int row = blockIdx.x * 64 + i;
        if (tid < 16) xs4[tid] = ((const float4*)(x + (size_t)row * EMB_D))[tid];
        __syncthreads();
        if (tid == 0) {
            const float* xf = (const float*)xs4;
            float r[8];
#pragma unroll
            for (int j = 0; j < 8; ++j) r[j] = __fmul_rn(xf[j], xf[j]);
#pragma unroll
            for (int t = 1; t < 8; ++t)
#pragma unroll
                for (int j = 0; j < 8; ++j)
                    r[j] = __fadd_rn(r[j], __fmul_rn(xf[t * 8 + j], xf[t * 8 + j]));
            xsqs = __fadd_rn(
                __fadd_rn(__fadd_rn(r[0], r[1]), __fadd_rn(r[2], r[3])),
                __fadd_rn(__fadd_rn(r[4], r[5]), __fadd_rn(r[6], r[7])));
        }
        __syncthreads();
        const float xsq = xsqs;

        float bs = INFINITY;
        int   bk = K;
        for (int t = 0; t < 4; ++t) {
            const int k = wave * (K >> 2) + t * 64 + lane;
            const float4* wr4 = (const float4*)(w + (size_t)k * EMB_D);
            double a0 = 0.0, a1 = 0.0, a2 = 0.0, a3 = 0.0;
#pragma unroll
            for (int q = 0; q < EMB_D / 4; ++q) {
                const float4 xv = xs4[q];
                const float4 wv = wr4[q];
                a0 = fma((double)xv.x, (double)wv.x, a0);
                a1 = fma((double)xv.y, (double)wv.y, a1);
                a2 = fma((double)xv.z, (double)wv.z, a2);
                a3 = fma((double)xv.w, (double)wv.w, a3);
            }
            const float mf = (float)((a0 + a1) + (a2 + a3));
            const float t2 = __fsub_rn(xsq, __fmul_rn(2.0f, mf));
            const float sc = __fadd_rn(t2, wsq[k]);
            if (sc < bs || (sc == bs && k < bk)) { bs = sc; bk = k; }
        }
        ls[tid] = bs; lk[tid] = bk;
        __syncthreads();
        if (wave == 0) {
            float gs = ls[lane];
            int   gk = lk[lane];
#pragma unroll
            for (int c = 1; c < 4; ++c) {
                const float os = ls[c * 64 + lane];
                const int   ok = lk[c * 64 + lane];
                if (os < gs || (os == gs && ok < gk)) { gs = os; gk = ok; }
            }
#pragma unroll
            for (int off = 32; off > 0; off >>= 1) {
                const float os = __shfl_down(gs, off);
                const int   ok = __shfl_down(gk, off);
                if (os < gs || (os == gs && ok < gk)) { gs = os; gk = ok; }
            }
            if (lane == 0) kf[i] = gk;
        }
        __syncthreads();
    }

    // ---- phase 3: indices + gather + loss (atomic accumulate) ----
    if (tid < 64) {
        const int row = blockIdx.x * 64 + tid;
        out[(size_t)N * EMB_D + row] = (float)kf[tid];
    }
    float lpart = 0.f;
#pragma unroll
    for (int rep = 0; rep < 4; ++rep) {
        int f4   = rep * 256 + tid;     // 0..1023
        int rr   = f4 >> 4;             // local row 0..63
        int c    = f4 & 15;
        int k    = kf[rr];
        int grow = blockIdx.x * 64 + rr;
        float4 wv = ((const float4*)(w + (size_t)k * EMB_D))[c];
        float4 xq = ((const float4*)(x + (size_t)grow * EMB_D))[c];
        ((float4*)out)[(size_t)grow * (EMB_D / 4) + c] = wv;
        float dx = wv.x - xq.x, dy = wv.y - xq.y;
        float dz = wv.z - xq.z, dw = wv.w - xq.w;
        lpart += dx * dx + dy * dy + dz * dz + dw * dw;
    }
#pragma unroll
    for (int off = 32; off > 0; off >>= 1) lpart += __shfl_down(lpart, off);
    __shared__ float lred[4];
    if (lane == 0) lred[wave] = lpart;
    __syncthreads();
    if (tid == 0)
        atomicAdd(loss_out, ((lred[0] + lred[1]) + (lred[2] + lred[3])) * scale);
}

extern "C" void kernel_launch(void* const* d_in, const int* in_sizes, int n_in,
                              void* d_out, int out_size, void* d_ws, size_t ws_size,
                              hipStream_t stream) {
    const float* x = (const float*)d_in[0];
    const float* w = (const float*)d_in[1];
    float* out = (float*)d_out;
    const int xsz = in_sizes[0];   // N * D
    const int wsz = in_sizes[1];   // K * D
    const int N   = xsz / EMB_D;   // 65536
    const int K   = wsz / EMB_D;   // 1024
    const int NB  = N / 64;        // 1024
    float* loss_out = out + (size_t)N * EMB_D + N;

    // ws: [wsq Kf][wt_hi K*64 u16][wt_lo K*64 u16]
    float* wsq = (float*)d_ws;
    unsigned short* wt_hi = (unsigned short*)(wsq + K);
    unsigned short* wt_lo = wt_hi + (size_t)K * EMB_D;

    vq_prepw_kernel<<<(K * 8 + 255) / 256, 256, 0, stream>>>(w, wt_hi, wt_lo,
                                                             wsq, loss_out, K);
    vq_fused_kernel<<<NB, 256, 0, stream>>>(x, wt_hi, wt_lo, wsq, w, out,
                                            loss_out, K, N,
                                            1.25f / (float)xsz);
}